// Round 9
// baseline (1053.100 us; speedup 1.0000x reference)
//
#include <hip/hip_runtime.h>

// Problem constants: B=64, T=256, V=4096, H=512
// Inputs: x[B*T] i32, Wxh[V,H] f32, Whh[H,H] f32, bh[H] f32, Wo[H,V] f32, Bo[V] f32
// Output: out[B,T,V] f32 = (scan hs) @ Wo + Bo

typedef __fp16 half2_t __attribute__((ext_vector_type(2)));
typedef __attribute__((ext_vector_type(8))) short short8;   // 8 bf16 (MFMA A/B frag)
typedef __attribute__((ext_vector_type(4))) float f32x4;    // MFMA C/D frag

__device__ __forceinline__ unsigned short f32_to_bf16(float f) {
  unsigned int u = __builtin_bit_cast(unsigned int, f);
  u = (u + 0x7FFFu + ((u >> 16) & 1u)) >> 16;  // RNE
  return (unsigned short)u;
}

__device__ __forceinline__ unsigned int pack_f16x2(float a, float b) {
  half2_t h = __builtin_amdgcn_cvt_pkrtz(a, b);
  return __builtin_bit_cast(unsigned int, h);
}

__device__ __forceinline__ float fdot2_(unsigned int w, unsigned int h, float acc) {
  return __builtin_amdgcn_fdot2(__builtin_bit_cast(half2_t, w),
                                __builtin_bit_cast(half2_t, h), acc, false);
}

__device__ __forceinline__ void glds16(const void* g, void* lds) {
  __builtin_amdgcn_global_load_lds(
      (const __attribute__((address_space(1))) unsigned int*)g,
      (__attribute__((address_space(3))) unsigned int*)lds, 16, 0, 0);
}

// ---------------------------------------------------------------------------
// Prep 1: Whh -> WhhP6. u32 flat idx = U*4 + e where
// U = ((i*8 + c)*4 + o)*128 + g   (i=k-eighth, c=chunk 0..7, o=colgrp, g=lane)
// holds pair p = 32*i + 4*c + e (h elems 2p,2p+1) of column j = o*128 + g.
// Scan thread (g,i) loading (c,o) at consecutive g -> coalesced 16B.
// ---------------------------------------------------------------------------
__global__ __launch_bounds__(256) void pack_whh6(const float* __restrict__ Whh,
                                                 unsigned int* __restrict__ WhhP6) {
  int idx = blockIdx.x * 256 + threadIdx.x;  // 131072 u32 total
  int e = idx & 3;
  int U = idx >> 2;
  int g = U & 127;
  int o = (U >> 7) & 3;
  int c = (U >> 9) & 7;
  int i = U >> 12;
  int p = 32 * i + 4 * c + e;   // f16-pair index 0..255
  int j = o * 128 + g;          // column
  float f0 = Whh[(2 * p) * 512 + j];
  float f1 = Whh[(2 * p + 1) * 512 + j];
  WhhP6[idx] = pack_f16x2(f0, f1);
}

// ---------------------------------------------------------------------------
// Prep 2: Wo [h][v] f32 -> WoT [v][h] bf16
// ---------------------------------------------------------------------------
__global__ __launch_bounds__(256) void transpose_wo(const float* __restrict__ Wo,
                                                    unsigned short* __restrict__ WoT) {
  __shared__ float tile[64][65];
  const int tv = blockIdx.x;   // 0..63  (V/64)
  const int th = blockIdx.y;   // 0..7   (H/64)
  const int tid = threadIdx.x;
  const int c = tid & 63, r4 = tid >> 6;
#pragma unroll
  for (int p = 0; p < 16; ++p) {
    int hl = p * 4 + r4;
    tile[hl][c] = Wo[(size_t)(th * 64 + hl) * 4096 + tv * 64 + c];
  }
  __syncthreads();
#pragma unroll
  for (int p = 0; p < 16; ++p) {
    int vl = p * 4 + r4;
    WoT[(size_t)(tv * 64 + vl) * 512 + th * 64 + c] = f32_to_bf16(tile[c][vl]);
  }
}

// ---------------------------------------------------------------------------
// Recurrence v6: PURE STREAMING, max TLP. R2-R8 lesson: weights won't stay in
// registers; cross-block sync is 19us/step; so the scan is an L2->CU stream
// problem (512 KB Whh/step/block). R6's 92 B/cyc was caused by a mid-step asm
// fence serializing L2 round-trips + only 8 waves. Here: 1024 threads (16
// waves = 4/SIMD, natural 128-VGPR target), ONE clobber at loop top (blocks
// LICM only), 28 independent streamed uint4/thread/step in straight-line
// unrolled code -> deep vmcnt pipeline; chunk 0 (64 KB) LDS-resident as a
// bandwidth hedge. Thread (g=tid&127, i=tid>>7): 4 cols {o*128+g} over
// k-eighth i. Partials [8][512] reduced by tid<512. 2 barriers/step.
// ---------------------------------------------------------------------------
#define DD4(A, W, H) do { A = fdot2_(W.x, H.x, A); A = fdot2_(W.y, H.y, A); \
                          A = fdot2_(W.z, H.z, A); A = fdot2_(W.w, H.w, A); } while (0)

__global__ __launch_bounds__(1024, 4)
void rnn_scan6(const int* __restrict__ x,
               const float* Wxh,
               const unsigned int* WhhP6,
               const float* __restrict__ bh,
               unsigned short* hs) {
  __shared__ uint4 wlds[4096];   // 64 KB: weight chunk c=0 (all i,o,g)
  __shared__ uint4 hbuf[128];    // 2 x 512 h f16 (double buffer)
  __shared__ float pbuf[4096];   // partials [i][j]
  __shared__ int toks[256];
  const int b = blockIdx.x;
  const int tid = threadIdx.x;
  const int g = tid & 127;
  const int i = tid >> 7;        // k-eighth (wave-uniform)
  const uint4* W4 = (const uint4*)WhhP6;

  // stage chunk 0: each thread copies its own 4 uint4 (coalesced)
#pragma unroll
  for (int o = 0; o < 4; ++o)
    wlds[(i * 4 + o) * 128 + g] = W4[((i * 8 + 0) * 4 + o) * 128 + g];
  if (tid < 64) hbuf[tid] = make_uint4(0u, 0u, 0u, 0u);  // h0 = 0 (buf 0)
  if (tid < 256) toks[tid] = x[b * 256 + tid];
  const float bhj = (tid < 512) ? bh[tid] : 0.f;
  __syncthreads();

  unsigned short* hb16 = (unsigned short*)hbuf;  // [2][512] u16 view

  for (int t = 0; t < 256; ++t) {
    asm volatile("" ::: "memory");  // block LICM of loop-invariant weight loads
    const uint4* hb = hbuf + (t & 1) * 64;
    const int tok = toks[t];
    const float xv = (tid < 512) ? Wxh[(size_t)tok * 512 + tid] : 0.f;

    float a0 = 0.f, a1 = 0.f, a2 = 0.f, a3 = 0.f;
    // chunk 0 from LDS
    {
      const uint4 hc = hb[i * 8 + 0];
      const uint4 w0 = wlds[(i * 4 + 0) * 128 + g];
      const uint4 w1 = wlds[(i * 4 + 1) * 128 + g];
      const uint4 w2 = wlds[(i * 4 + 2) * 128 + g];
      const uint4 w3 = wlds[(i * 4 + 3) * 128 + g];
      DD4(a0, w0, hc); DD4(a1, w1, hc); DD4(a2, w2, hc); DD4(a3, w3, hc);
    }
    // chunks 1..7 streamed from L2: straight-line, no fences -> deep pipeline
#pragma unroll
    for (int c = 1; c < 8; ++c) {
      const uint4 hc = hb[i * 8 + c];
      const uint4 w0 = W4[((i * 8 + c) * 4 + 0) * 128 + g];
      const uint4 w1 = W4[((i * 8 + c) * 4 + 1) * 128 + g];
      const uint4 w2 = W4[((i * 8 + c) * 4 + 2) * 128 + g];
      const uint4 w3 = W4[((i * 8 + c) * 4 + 3) * 128 + g];
      DD4(a0, w0, hc); DD4(a1, w1, hc); DD4(a2, w2, hc); DD4(a3, w3, hc);
    }

    pbuf[i * 512 + 0 * 128 + g] = a0;
    pbuf[i * 512 + 1 * 128 + g] = a1;
    pbuf[i * 512 + 2 * 128 + g] = a2;
    pbuf[i * 512 + 3 * 128 + g] = a3;
    __syncthreads();

    if (tid < 512) {  // finalize output j = tid
      float s = pbuf[tid] + pbuf[tid + 512] + pbuf[tid + 1024] + pbuf[tid + 1536] +
                pbuf[tid + 2048] + pbuf[tid + 2560] + pbuf[tid + 3072] + pbuf[tid + 3584];
      const float h = tanhf(xv + s + bhj);
      hs[(size_t)(b * 256 + t) * 512 + tid] = f32_to_bf16(h);
      half2_t hp2 = __builtin_amdgcn_cvt_pkrtz(h, h);
      hb16[((t & 1) ^ 1) * 512 + tid] =
          (unsigned short)(__builtin_bit_cast(unsigned int, hp2) & 0xFFFFu);
    }
    __syncthreads();  // next h complete; pbuf reusable
  }
}

// ---------------------------------------------------------------------------
// Output GEMM: C[16384,4096] = A[16384,512](bf16) @ WoT^T + Bo.  m97 structure.
// ---------------------------------------------------------------------------
__global__ __launch_bounds__(256) void gemm_out(const unsigned short* __restrict__ A,
                                                const unsigned short* __restrict__ Bt,
                                                const float* __restrict__ Bo,
                                                float* __restrict__ C) {
  __shared__ alignas(16) unsigned short As[128 * 32];
  __shared__ alignas(16) unsigned short Bs[128 * 32];
  const int tid = threadIdx.x;
  const int lane = tid & 63, wid = tid >> 6;
  const int bn = blockIdx.x & 31, bm = blockIdx.x >> 5;
  const int wr = wid >> 1, wc = wid & 1;

  f32x4 acc[4][4] = {};

  const unsigned short* Ag = A + (size_t)(bm * 128 + (tid >> 2)) * 512 + (tid & 3) * 8;
  const unsigned short* Bg = Bt + (size_t)(bn * 128 + (tid >> 2)) * 512 + (tid & 3) * 8;
  char* AsW = (char*)As + wid * 1024;
  char* BsW = (char*)Bs + wid * 1024;

  const int laneRow = lane & 15;
  const int k0 = (lane >> 4) * 8;

  for (int kt = 0; kt < 16; ++kt) {
    __syncthreads();
    const unsigned short* a0 = Ag + kt * 32;
    const unsigned short* b0 = Bg + kt * 32;
    glds16(a0,            AsW);
    glds16(a0 + 64 * 512, AsW + 4096);
    glds16(b0,            BsW);
    glds16(b0 + 64 * 512, BsW + 4096);
    __syncthreads();

    short8 af[4], bf[4];
#pragma unroll
    for (int f = 0; f < 4; ++f)
      af[f] = *(const short8*)&As[(wr * 64 + f * 16 + laneRow) * 32 + k0];
#pragma unroll
    for (int f = 0; f < 4; ++f)
      bf[f] = *(const short8*)&Bs[(wc * 64 + f * 16 + laneRow) * 32 + k0];
#pragma unroll
    for (int fm = 0; fm < 4; ++fm)
#pragma unroll
      for (int fn = 0; fn < 4; ++fn)
        acc[fm][fn] = __builtin_amdgcn_mfma_f32_16x16x32_bf16(af[fm], bf[fn], acc[fm][fn], 0, 0, 0);
  }

  const int mg0 = bm * 128 + wr * 64, ng0 = bn * 128 + wc * 64;
#pragma unroll
  for (int fn = 0; fn < 4; ++fn) {
    const int col = ng0 + fn * 16 + laneRow;
    const float bo = Bo[col];
#pragma unroll
    for (int fm = 0; fm < 4; ++fm) {
      const int row0 = mg0 + fm * 16 + (lane >> 4) * 4;
#pragma unroll
      for (int r = 0; r < 4; ++r)
        C[(size_t)(row0 + r) * 4096 + col] = acc[fm][fn][r] + bo;
    }
  }
}

// ---------------------------------------------------------------------------
extern "C" void kernel_launch(void* const* d_in, const int* in_sizes, int n_in,
                              void* d_out, int out_size, void* d_ws, size_t ws_size,
                              hipStream_t stream) {
  (void)in_sizes; (void)n_in; (void)out_size; (void)ws_size;
  const int* x = (const int*)d_in[0];
  const float* Wxh = (const float*)d_in[1];
  const float* Whh = (const float*)d_in[2];
  const float* bh = (const float*)d_in[3];
  const float* Wo = (const float*)d_in[4];
  const float* Bo = (const float*)d_in[5];
  float* out = (float*)d_out;

  // workspace: WhhP6 512KB | WoT 4MB | hs 16MB
  unsigned int* WhhP6 = (unsigned int*)d_ws;
  unsigned short* WoT = (unsigned short*)((char*)d_ws + 524288);
  unsigned short* hs = (unsigned short*)((char*)d_ws + 4718592);

  hipLaunchKernelGGL(pack_whh6, dim3(512), dim3(256), 0, stream, Whh, WhhP6);
  hipLaunchKernelGGL(transpose_wo, dim3(64, 8), dim3(256), 0, stream, Wo, WoT);
  hipLaunchKernelGGL(rnn_scan6, dim3(64), dim3(1024), 0, stream, x, Wxh, WhhP6, bh, hs);
  hipLaunchKernelGGL(gemm_out, dim3(4096), dim3(256), 0, stream, hs, WoT, Bo, out);
}